// Round 1
// baseline (99.146 us; speedup 1.0000x reference)
//
#include <hip/hip_runtime.h>
#include <math.h>

#define D_FEAT 128
#define D_DOT 4

// Kernel 1: pn[v][k] = sum_d n[v][d] * W[k][d]   (raw projection, no bias/scale)
// 16 lanes per row, 4 rows per wave. Each lane loads 2x float4 (8 floats).
__global__ __launch_bounds__(256) void node_proj_kernel(
    const float* __restrict__ n,
    const float* __restrict__ W,
    float* __restrict__ pn,
    int n_nodes)
{
    const int lane = threadIdx.x & 63;
    const int sub  = lane & 15;   // position within 16-lane group
    const int grp  = lane >> 4;   // 0..3: which row of this wave's quartet
    const int wave = (blockIdx.x * blockDim.x + threadIdx.x) >> 6;
    const int n_waves = (gridDim.x * blockDim.x) >> 6;

    // Hoist this lane's W fragment (constant across rows)
    float4 wlo[D_DOT], whi[D_DOT];
#pragma unroll
    for (int k = 0; k < D_DOT; ++k) {
        wlo[k] = *reinterpret_cast<const float4*>(&W[k * D_FEAT + sub * 4]);
        whi[k] = *reinterpret_cast<const float4*>(&W[k * D_FEAT + 64 + sub * 4]);
    }

    for (int base = wave * 4; base < n_nodes; base += n_waves * 4) {
        const int row = base + grp;
        float a[D_DOT] = {0.f, 0.f, 0.f, 0.f};
        if (row < n_nodes) {
            const float4 xlo = *reinterpret_cast<const float4*>(&n[(size_t)row * D_FEAT + sub * 4]);
            const float4 xhi = *reinterpret_cast<const float4*>(&n[(size_t)row * D_FEAT + 64 + sub * 4]);
#pragma unroll
            for (int k = 0; k < D_DOT; ++k) {
                a[k] = xlo.x * wlo[k].x + xlo.y * wlo[k].y + xlo.z * wlo[k].z + xlo.w * wlo[k].w
                     + xhi.x * whi[k].x + xhi.y * whi[k].y + xhi.z * whi[k].z + xhi.w * whi[k].w;
            }
        }
        // butterfly reduce within each 16-lane group (xor masks 8,4,2,1 stay in-group)
#pragma unroll
        for (int m = 8; m >= 1; m >>= 1) {
#pragma unroll
            for (int k = 0; k < D_DOT; ++k) a[k] += __shfl_xor(a[k], m, 64);
        }
        if (sub == 0 && row < n_nodes) {
            *reinterpret_cast<float4*>(&pn[(size_t)row * D_DOT]) =
                make_float4(a[0], a[1], a[2], a[3]);
        }
    }
}

// Kernel 2: per edge — pe = W·e[edge]; hs = .5*(pn[src]+pe)+b; hd = .5*(pn[dst]+pe)+b;
// out = sigmoid(hs·hd). Same 16-lane-per-edge layout.
__global__ __launch_bounds__(256) void edge_score_kernel(
    const float* __restrict__ e,
    const float* __restrict__ W,
    const float* __restrict__ bias,
    const float* __restrict__ pn,
    const int* __restrict__ src_idx,
    const int* __restrict__ dst_idx,
    float* __restrict__ out,
    int n_edges)
{
    const int lane = threadIdx.x & 63;
    const int sub  = lane & 15;
    const int grp  = lane >> 4;
    const int wave = (blockIdx.x * blockDim.x + threadIdx.x) >> 6;
    const int n_waves = (gridDim.x * blockDim.x) >> 6;

    float4 wlo[D_DOT], whi[D_DOT];
#pragma unroll
    for (int k = 0; k < D_DOT; ++k) {
        wlo[k] = *reinterpret_cast<const float4*>(&W[k * D_FEAT + sub * 4]);
        whi[k] = *reinterpret_cast<const float4*>(&W[k * D_FEAT + 64 + sub * 4]);
    }
    const float b0 = bias[0], b1 = bias[1], b2 = bias[2], b3 = bias[3];

    for (int base = wave * 4; base < n_edges; base += n_waves * 4) {
        const int edge = base + grp;
        float a[D_DOT] = {0.f, 0.f, 0.f, 0.f};
        if (edge < n_edges) {
            const float4 xlo = *reinterpret_cast<const float4*>(&e[(size_t)edge * D_FEAT + sub * 4]);
            const float4 xhi = *reinterpret_cast<const float4*>(&e[(size_t)edge * D_FEAT + 64 + sub * 4]);
#pragma unroll
            for (int k = 0; k < D_DOT; ++k) {
                a[k] = xlo.x * wlo[k].x + xlo.y * wlo[k].y + xlo.z * wlo[k].z + xlo.w * wlo[k].w
                     + xhi.x * whi[k].x + xhi.y * whi[k].y + xhi.z * whi[k].z + xhi.w * whi[k].w;
            }
        }
#pragma unroll
        for (int m = 8; m >= 1; m >>= 1) {
#pragma unroll
            for (int k = 0; k < D_DOT; ++k) a[k] += __shfl_xor(a[k], m, 64);
        }
        if (sub == 0 && edge < n_edges) {
            const int s = src_idx[edge];
            const int d = dst_idx[edge];
            const float4 ps = *reinterpret_cast<const float4*>(&pn[(size_t)s * D_DOT]);
            const float4 pd = *reinterpret_cast<const float4*>(&pn[(size_t)d * D_DOT]);
            float dot = 0.f;
            {
                float hs = 0.5f * (ps.x + a[0]) + b0, hd = 0.5f * (pd.x + a[0]) + b0; dot += hs * hd;
            }
            {
                float hs = 0.5f * (ps.y + a[1]) + b1, hd = 0.5f * (pd.y + a[1]) + b1; dot += hs * hd;
            }
            {
                float hs = 0.5f * (ps.z + a[2]) + b2, hd = 0.5f * (pd.z + a[2]) + b2; dot += hs * hd;
            }
            {
                float hs = 0.5f * (ps.w + a[3]) + b3, hd = 0.5f * (pd.w + a[3]) + b3; dot += hs * hd;
            }
            out[edge] = 1.0f / (1.0f + expf(-dot));
        }
    }
}

extern "C" void kernel_launch(void* const* d_in, const int* in_sizes, int n_in,
                              void* d_out, int out_size, void* d_ws, size_t ws_size,
                              hipStream_t stream) {
    const float* n    = (const float*)d_in[0];
    const float* e    = (const float*)d_in[1];
    const float* W    = (const float*)d_in[2];
    const float* bias = (const float*)d_in[3];
    const int*   src  = (const int*)d_in[4];
    const int*   dst  = (const int*)d_in[5];
    float* out = (float*)d_out;

    const int n_nodes = in_sizes[0] / D_FEAT;
    const int n_edges = in_sizes[1] / D_FEAT;

    float* pn = (float*)d_ws;  // n_nodes * 4 floats = 1.6 MB

    node_proj_kernel<<<1024, 256, 0, stream>>>(n, W, pn, n_nodes);
    edge_score_kernel<<<2048, 256, 0, stream>>>(e, W, bias, pn, src, dst, out, n_edges);
}